// Round 9
// baseline (490.629 us; speedup 1.0000x reference)
//
#include <hip/hip_runtime.h>

typedef unsigned short u16;
typedef unsigned int u32;
typedef __attribute__((ext_vector_type(8))) short short8;
typedef __attribute__((ext_vector_type(4))) float floatx4;

static constexpr int M = 16384, N = 2048, K = 2048;

// ---- helpers -------------------------------------------------------------

__device__ inline u16 f32_to_bf16(float x) {
    u32 u = __float_as_uint(x);
    u += 0x7FFFu + ((u >> 16) & 1u);
    return (u16)(u >> 16);
}

// RNE round to e4m3 grid; valid for x in [2^-6, 448] (normal e4m3 range,
// guaranteed by the preceding clip). 3 mantissa bits -> round at fp32 bit 20.
__device__ inline float e4m3_rne(float x) {
    u32 u = __float_as_uint(x);
    u += 0x7FFFFu + ((u >> 20) & 1u);
    u &= 0xFFF00000u;
    return __uint_as_float(u);
}

// decode fp4 e2m1 code (4 bits incl. sign) -> float {0,.5,1,1.5,2,3,4,6}*sign
__device__ inline float fp4_dec(u32 c) {
    u32 e = (c >> 1) & 3u;
    float m = (float)(c & 1u);
    float v = e ? (2.0f + m) * (float)(1u << e) * 0.25f : 0.5f * m;
    return (c & 8u) ? -v : v;
}

// reference fp4_121_positive with jnp.round == RNE == rintf
__device__ inline float fp4_round_mag(float a) {
    if (a < 2.0f) return rintf(2.0f * a) * 0.5f;
    if (a < 4.0f) return rintf(a);
    return 2.0f * rintf(a * 0.5f);
}

__device__ inline float pts_from_amax(float amax) {
    // clip(amax / 448, 2^-6, 448); true IEEE division to match reference
    return fminf(fmaxf(amax / 448.0f, 0.015625f), 448.0f);
}

// ---- kernel 1: partial amax + weight dequant ----------------------------
// Weight dequant is independent of amax and rides along. NO device-scope
// fences (R5: last-block-finalize pattern cost +100us in L2 writebacks).

__global__ __launch_bounds__(256) void amax_part(
    const float4* __restrict__ x, float* __restrict__ part,
    const int* __restrict__ wp, const float* __restrict__ wsc,
    const float* __restrict__ wgs, u16* __restrict__ wq) {
    int idx = blockIdx.x * blockDim.x + threadIdx.x;   // grid 2048x256
    float m = 0.0f;
#pragma unroll 4
    for (int it = 0; it < 16; ++it) {                   // 8.4M float4
        float4 v = x[idx + it * 524288];
        m = fmaxf(m, fmaxf(fmaxf(fabsf(v.x), fabsf(v.y)),
                           fmaxf(fabsf(v.z), fabsf(v.w))));
    }

    // weight dequant: N*K/2 = 2,097,152 packed bytes, 4 per thread
    float ginv = wgs[0];
#pragma unroll
    for (int g = 0; g < 4; g++) {
        int i = idx + g * 524288;
        int n = i >> 10;                                // Khalf = 1024
        int kb = i & 1023;
        u32 byte = (u32)wp[i] & 0xFFu;
        float scale = wsc[(size_t)n * (K / 16) + (kb >> 3)] / ginv;
        float lo = fp4_dec(byte & 0xFu) * scale;
        float hi = fp4_dec((byte >> 4) & 0xFu) * scale;
        ((u32*)wq)[i] = (u32)f32_to_bf16(lo) | ((u32)f32_to_bf16(hi) << 16);
    }

#pragma unroll
    for (int off = 32; off > 0; off >>= 1)
        m = fmaxf(m, __shfl_down(m, off));
    __shared__ float sm[4];
    if ((threadIdx.x & 63) == 0) sm[threadIdx.x >> 6] = m;
    __syncthreads();
    if (threadIdx.x == 0)
        part[blockIdx.x] = fmaxf(fmaxf(sm[0], sm[1]), fmaxf(sm[2], sm[3]));
}

// ---- kernel 1b: finalize amax (1 block, 1024 threads, 2048 partials) ----

__global__ void amax_fin(const float* __restrict__ part, u32* __restrict__ out) {
    int t = threadIdx.x;
    float m = fmaxf(part[t], part[t + 1024]);
#pragma unroll
    for (int off = 32; off > 0; off >>= 1)
        m = fmaxf(m, __shfl_down(m, off));
    __shared__ float sm[16];
    if ((t & 63) == 0) sm[t >> 6] = m;
    __syncthreads();
    if (t < 16) {
        m = sm[t];
#pragma unroll
        for (int off = 8; off > 0; off >>= 1)
            m = fmaxf(m, __shfl_down(m, off));
        if (t == 0) *out = __float_as_uint(m);
    }
}

// ---- kernel 2: QDQ x -> bf16 A = lp * sbs (exact in bf16) ---------------

__global__ __launch_bounds__(256) void prep(
    const float4* __restrict__ x, uint2* __restrict__ aq,
    const u32* __restrict__ amax_bits) {
    int idx0 = blockIdx.x * blockDim.x + threadIdx.x;
    float pts = pts_from_amax(__uint_as_float(*amax_bits));

#pragma unroll 4
    for (int it = 0; it < 16; ++it) {
        int idx = idx0 + it * 524288;
        float4 v = x[idx];                              // L3-warm from amax

        float bm = fmaxf(fmaxf(fabsf(v.x), fabsf(v.y)),
                         fmaxf(fabsf(v.z), fabsf(v.w)));
        bm = fmaxf(bm, __shfl_xor(bm, 1));
        bm = fmaxf(bm, __shfl_xor(bm, 2));              // 4-lane group = 16-block

        float bs = bm / 6.0f;
        float sbs = e4m3_rne(fminf(fmaxf(bs / pts, 0.015625f), 448.0f));
        float ts = pts * sbs;

        float vf[4] = {v.x, v.y, v.z, v.w};
        u16 o[4];
#pragma unroll
        for (int i = 0; i < 4; i++) {
            float s = vf[i] / ts;                       // IEEE div, matches ref
            s = fminf(fmaxf(s, -6.0f), 6.0f);
            float lp = copysignf(fp4_round_mag(fabsf(s)), s);
            o[i] = f32_to_bf16(lp * sbs);               // exact product
        }
        aq[idx] = *(const uint2*)o;
    }
}

// ---- kernel 3: bf16 GEMM v3b -- 8-phase read-ahead, FIXED stage ledger --
//
// R8 failed (absmax 191): the stage schedule treated LDS halves as if
// selected by MFMA quadrant; actually RDA reads half wm and RDB reads half
// (wn>>1) -- so the FIRST read of a buf touches BOTH halves (across waves).
// Corrected deadlines: all 4 halves of a buf confirmed before the buf's
// first read phase.
//
// Reads (1 phase ahead of consuming MFMA, unchanged from R8):
//   P1:B(X,1) P2:A(X,1) P3:B(Y,0)* P4:A(Y,0)* P5:B(Y,1) P6:A(Y,1)
//   P7:B(X',0)* P8:A(X',0)*            (* = first read of that buf/mat)
// MFMA: P1:(X,0,0) P2:(X,0,1) P3:(X,1,1) P4:(X,1,0)
//       P5:(Y,0,0) P6:(Y,0,1) P7:(Y,1,1) P8:(Y,1,0)
// Stages (2 loads each): P1:Y.A1  P2:X'.B0 P3:X'.B1 P4:X'.A0 P5:X'.A1
//                        P6:Y'.B0 P7:Y'.B1 P8:Y'.A0 (Y'.A1 at next P1)
// vmcnt: P3,P7 = vmcnt(4); all others vmcnt(6). Ledger (2 loads/phase):
//   P6 vmcnt(6) confirms <=P3: X'.B0(P2),X'.B1(P3) -> P7 B-read safe
//   P7 vmcnt(4) confirms <=P5: X'.A0(P4),X'.A1(P5) -> P8 A-read safe
//   next-P2 vmcnt(6) confirms <=P7: Y'.B0(P6),Y'.B1(P7) -> P3 safe
//   next-P3 vmcnt(4) confirms <=nextP1: Y'.A0(P8),Y'.A1(nP1) -> P4 safe
// Each confirm precedes the barrier before the read -> cross-wave safe.
// WAR: every stage is >=1 barrier+MFMA-phase after the last read-issue of
// the content it overwrites (R6's proven gap). MFMA order identical to R6
// -> bit-identical C.

#define GLDS(g, l)                                                              \
    __builtin_amdgcn_global_load_lds(                                           \
        (const __attribute__((address_space(1))) unsigned int*)(g),             \
        (__attribute__((address_space(3))) unsigned int*)(l), 16, 0, 0)

__global__ __launch_bounds__(512, 2) void gemm_bt(
    const u16* __restrict__ A, const u16* __restrict__ B,
    float* __restrict__ C, const u32* __restrict__ amax_bits)
{
    // [buf][mat A=0/B=1][half][128 rows * 64 cols] bf16, 16 KiB per half
    __shared__ u16 sh[2][2][2][8192];

    const int tid = threadIdx.x;
    const int w = tid >> 6, lane = tid & 63;

    // XCD swizzle (512 blocks, 512%8==0 -> bijective)
    const int id = blockIdx.x;
    const int xcd = id & 7;
    const int local = id >> 3;                   // 0..63 per XCD
    const int bm = xcd * 8 + (local >> 3);       // 0..63  (M/256)
    const int bn = local & 7;                    // 0..7   (N/256)

    const int wm = w >> 2, wn = w & 3;           // 2x4 wave grid
    const int r16 = lane & 15, q = lane >> 4;

    floatx4 acc[8][4] = {};

    // ---- swizzled fragment read offsets (u16 units) ----
    const int swz = (r16 & 7) << 4;                          // byte XOR value
    const int aoff0 = r16 * 64 + (((q * 16) ^ swz) >> 1);          // ks=0
    const int aoff1 = r16 * 64 + (((64 + q * 16) ^ swz) >> 1);     // ks=1

    // ---- staging source pointers (pre-swizzled per lane) ----
    const int srow8 = lane >> 3;                             // 0..7
    const int scol = ((lane & 7) ^ srow8) * 8;               // u16 units
    const u16* gA[2], * gB[2];
    gA[0] = A + (size_t)(bm * 256 + (w * 2 + 0) * 8 + srow8) * K + scol;
    gA[1] = A + (size_t)(bm * 256 + (w * 2 + 1) * 8 + srow8) * K + scol;
    gB[0] = B + (size_t)(bn * 256 + (w * 2 + 0) * 8 + srow8) * K + scol;
    gB[1] = B + (size_t)(bn * 256 + (w * 2 + 1) * 8 + srow8) * K + scol;

#define STG(buf, mat, half, ktc) do {                                           \
        const u16* _s0 = ((mat) ? gB[0] : gA[0]) + (size_t)(half) * 128 * K + (ktc); \
        const u16* _s1 = ((mat) ? gB[1] : gA[1]) + (size_t)(half) * 128 * K + (ktc); \
        GLDS(_s0, &sh[buf][mat][half][w * 1024]);                               \
        GLDS(_s1, &sh[buf][mat][half][w * 1024 + 512]);                         \
    } while (0)

    short8 aF[2][4][2];        // [set][i][ks] ; sets ping-pong per A-load
    short8 bF[2][2][2][2];     // [buf][Qb][j][ks]

#define RDA(buf, Qa, s) do {                                                    \
        const u16* _ar = &sh[buf][0][wm][(Qa) * 4096];                          \
        _Pragma("unroll") for (int _i = 0; _i < 4; _i++) {                      \
            aF[s][_i][0] = *(const short8*)(_ar + _i * 1024 + aoff0);           \
            aF[s][_i][1] = *(const short8*)(_ar + _i * 1024 + aoff1); }         \
    } while (0)

#define RDB(buf, Qb) do {                                                       \
        const u16* _br = &sh[buf][1][wn >> 1][(wn & 1) * 4096 + (Qb) * 2048];   \
        _Pragma("unroll") for (int _j = 0; _j < 2; _j++) {                      \
            bF[buf][Qb][_j][0] = *(const short8*)(_br + _j * 1024 + aoff0);     \
            bF[buf][Qb][_j][1] = *(const short8*)(_br + _j * 1024 + aoff1); }   \
    } while (0)

#define MMAQ(s, buf, Qa, Qb)                                                    \
        _Pragma("unroll") for (int _i = 0; _i < 4; _i++)                        \
        _Pragma("unroll") for (int _j = 0; _j < 2; _j++)                        \
        _Pragma("unroll") for (int _k = 0; _k < 2; _k++)                        \
            acc[(Qa) * 4 + _i][(Qb) * 2 + _j] =                                 \
                __builtin_amdgcn_mfma_f32_16x16x32_bf16(                        \
                    aF[s][_i][_k], bF[buf][Qb][_j][_k],                         \
                    acc[(Qa) * 4 + _i][(Qb) * 2 + _j], 0, 0, 0)

#define VM6 do { asm volatile("s_waitcnt vmcnt(6)" ::: "memory"); } while (0)
#define VM4 do { asm volatile("s_waitcnt vmcnt(4)" ::: "memory"); } while (0)
#define BARX do { __builtin_amdgcn_sched_barrier(0);                            \
                  __builtin_amdgcn_s_barrier();                                 \
                  __builtin_amdgcn_sched_barrier(0); } while (0)
#define PRIO1 __builtin_amdgcn_s_setprio(1)
#define PRIO0 do { __builtin_amdgcn_s_setprio(0);                               \
                   __builtin_amdgcn_sched_barrier(0); } while (0)

    // ---- prologue: X0 fully + Y0.B0,Y0.B1,Y0.A0 (7 stages, 14 loads) ----
    STG(0, 1, 0, 0);                          // X0.B0   (loads 1-2)
    STG(0, 1, 1, 0);                          // X0.B1   (3-4)
    STG(0, 0, 0, 0);                          // X0.A0   (5-6)
    STG(0, 0, 1, 0);                          // X0.A1   (7-8)
    STG(1, 1, 0, 64);                         // Y0.B0   (9-10)
    STG(1, 1, 1, 64);                         // Y0.B1   (11-12)
    STG(1, 0, 0, 64);                         // Y0.A0   (13-14)
    asm volatile("s_waitcnt vmcnt(6)" ::: "memory");   // loads 1-8 = X0 landed
    __builtin_amdgcn_s_barrier();
    __builtin_amdgcn_sched_barrier(0);
    RDA(0, 0, 0);                             // A(X0,0) -> set 0
    RDB(0, 0);                                // B(X0,0)

#pragma unroll 1
    for (int it = 0; it < K / 128; ++it) {
        const int ktY  = (2 * it + 1) * 64;             // this Y tile (<=31)
        const int kx2  = 2 * it + 2, ky2 = 2 * it + 3;
        const int ktX2 = (kx2 <= 31 ? kx2 : 31) * 64;   // clamp: last-iter
        const int ktY2 = (ky2 <= 31 ? ky2 : 31) * 64;   // stages are dummies

        // P1
        RDB(0, 1);    STG(1, 0, 1, ktY);  VM6; BARX; PRIO1; MMAQ(0, 0, 0, 0); PRIO0;
        // P2
        RDA(0, 1, 1); STG(0, 1, 0, ktX2); VM6; BARX; PRIO1; MMAQ(0, 0, 0, 1); PRIO0;
        // P3
        RDB(1, 0);    STG(0, 1, 1, ktX2); VM4; BARX; PRIO1; MMAQ(1, 0, 1, 1); PRIO0;
        // P4
        RDA(1, 0, 0); STG(0, 0, 0, ktX2); VM6; BARX; PRIO1; MMAQ(1, 0, 1, 0); PRIO0;
        // P5
        RDB(1, 1);    STG(0, 0, 1, ktX2); VM6; BARX; PRIO1; MMAQ(0, 1, 0, 0); PRIO0;
        // P6
        RDA(1, 1, 1); STG(1, 1, 0, ktY2); VM6; BARX; PRIO1; MMAQ(0, 1, 0, 1); PRIO0;
        // P7
        RDB(0, 0);    STG(1, 1, 1, ktY2); VM4; BARX; PRIO1; MMAQ(1, 1, 1, 1); PRIO0;
        // P8
        RDA(0, 0, 0); STG(1, 0, 0, ktY2); VM6; BARX; PRIO1; MMAQ(1, 1, 1, 0); PRIO0;
    }

    // drain all in-flight stages before LDS is reused for C staging
    asm volatile("s_waitcnt vmcnt(0)" ::: "memory");
    __builtin_amdgcn_s_barrier();
    __builtin_amdgcn_sched_barrier(0);

    float pts = pts_from_amax(__uint_as_float(*amax_bits));

    // ---- LDS-staged coalesced C-write (parity-XOR: 2-way = free) ----
    float* stage = (float*)&sh[0][0][0][0] + w * 1024;
    const int erow = lane >> 4;              // 0..3
    const int ecol = lane & 15;              // 0..15
    float* Cb = C + (size_t)(bm * 256 + wm * 128) * N + bn * 256 + wn * 64;
#pragma unroll
    for (int i = 0; i < 8; i++) {
        // C/D layout (verified m89/m91): col = lane&15, row = (lane>>4)*4+reg
#pragma unroll
        for (int j = 0; j < 4; j++)
#pragma unroll
            for (int t = 0; t < 4; t++)
                stage[(q * 4 + t) * 64 + ((j * 16 + r16) ^ ((q & 1) << 4))] =
                    pts * acc[i][j][t];
        asm volatile("s_waitcnt lgkmcnt(0)" ::: "memory");  // writes landed
        __builtin_amdgcn_sched_barrier(0);
#pragma unroll
        for (int k4 = 0; k4 < 4; k4++) {
            float4 vv = *(const float4*)&stage[(k4 * 4 + erow) * 64 +
                                               ((ecol * 4) ^ ((k4 & 1) << 4))];
            *(float4*)&Cb[(size_t)(i * 16 + k4 * 4 + erow) * N + ecol * 4] = vv;
        }
        asm volatile("s_waitcnt lgkmcnt(0)" ::: "memory");  // reads done (WAR)
        __builtin_amdgcn_sched_barrier(0);
    }
}

// ---- launch --------------------------------------------------------------

extern "C" void kernel_launch(void* const* d_in, const int* in_sizes, int n_in,
                              void* d_out, int out_size, void* d_ws, size_t ws_size,
                              hipStream_t stream) {
    const float* x   = (const float*)d_in[0];
    const int*   wp  = (const int*)d_in[1];
    const float* wsc = (const float*)d_in[2];
    const float* wgs = (const float*)d_in[3];
    float* out = (float*)d_out;

    // workspace layout:
    //   +0      : amax bits (u32, written by amax_fin)
    //   +64     : 2048 float partial maxima
    //   +16384  : A bf16 [M*K]
    //   then    : B bf16 [N*K]
    u32*   amax_bits = (u32*)d_ws;
    float* part      = (float*)((char*)d_ws + 64);
    u16*   aq        = (u16*)((char*)d_ws + 16384);
    u16*   wq        = aq + (size_t)M * K;

    amax_part<<<2048, 256, 0, stream>>>((const float4*)x, part,
                                        wp, wsc, wgs, wq);
    amax_fin<<<1, 1024, 0, stream>>>(part, amax_bits);
    prep<<<2048, 256, 0, stream>>>((const float4*)x, (uint2*)aq, amax_bits);
    gemm_bt<<<512, 512, 0, stream>>>(aq, wq, out, amax_bits);
}